// Round 5
// baseline (167.716 us; speedup 1.0000x reference)
//
#include <hip/hip_runtime.h>

#define LN_EPS 1e-5f
#define LOG2E 1.44269504f
#define NHALF_LOG2E (-0.72134752f)

#if __has_builtin(__builtin_amdgcn_exp2f)
#define EXP2F(x) __builtin_amdgcn_exp2f(x)
#else
#define EXP2F(x) __expf((x) * 0.69314718f)
#endif

typedef float v2f __attribute__((ext_vector_type(2)));

// ---------------------------------------------------------------------------
// Transpose x (32 x KIN) -> xT (KIN x 32). idx = i*32 + b; writes coalesced.
// ---------------------------------------------------------------------------
template<int KIN>
__global__ __launch_bounds__(256)
void transpose_x(const float* __restrict__ x, float* __restrict__ xT)
{
    int idx = blockIdx.x * 256 + threadIdx.x;
    int i = idx >> 5, b = idx & 31;
    xT[idx] = x[b * KIN + i];
}

// ---------------------------------------------------------------------------
// Wavelet linear, lane = (batch-pair, i-subgroup). Block = 2 waves; wave w
// owns o = 2*blockIdx.x + w, i-range [si*RANGE, (si+1)*RANGE).
// prep (per-wave LDS): {inv, -t*inv} float2 + w float, computed once.
// Main loop: lane p=lane&15 -> batches 2p,2p+1; g=lane>>4 -> i = 4*st+g.
// Batch-pair math done in packed fp32 (v_pk_fma_f32): 5 packed VALU + 2 exp
// per iteration. x load float2/lane = 512 B contiguous per wave instr.
// Unroll 8 -> 8 global loads in flight/wave. launch_bounds(128,8): VGPR<=64,
// LDS 9.25KB*16blk = 148KB -> up to 32 waves/CU.
// Epilogue: 2 shuffles, lanes 0..15 store coalesced float2 to part[si][o][b].
// ---------------------------------------------------------------------------
template<int KIN, int S>
__global__ __launch_bounds__(128, 8)
void wav_layer(const float* __restrict__ xT, const float* __restrict__ w,
               const float* __restrict__ t, const float* __restrict__ s,
               float* __restrict__ part)
{
    constexpr int RANGE = KIN / S;     // i-values per wave
    constexpr int STEPS = RANGE / 4;
    constexpr int PREPS = RANGE / 64;
    __shared__ float2 prepA[2][RANGE];  // {inv, -t*inv}
    __shared__ float  prepW[2][RANGE];  // w

    const int wave = threadIdx.x >> 6;
    const int lane = threadIdx.x & 63;
    const int o    = (blockIdx.x << 1) + wave;
    const int si   = blockIdx.y;
    const int ibase = si * RANGE;

    const float* __restrict__ wp = w + (size_t)o * KIN + ibase;
    const float* __restrict__ tp = t + (size_t)o * KIN + ibase;
    const float* __restrict__ sp = s + (size_t)o * KIN + ibase;

#pragma unroll
    for (int r = 0; r < PREPS; ++r) {
        int il = r * 64 + lane;
        float wv = wp[il], tv = tp[il], sv = sp[il];
        float sig = __builtin_amdgcn_rcpf(1.f + EXP2F(-sv * LOG2E));
        float inv = __builtin_amdgcn_rcpf(fmaf(9.99f, sig, 0.01000001f));
        prepA[wave][il] = make_float2(inv, -tv * inv);
        prepW[wave][il] = wv;
    }
    __syncthreads();

    const int p = lane & 15, g = lane >> 4;
    const v2f* __restrict__ xp = (const v2f*)xT + (size_t)(ibase + g) * 16 + p;

    v2f acc = {0.f, 0.f};
#pragma unroll 8
    for (int st = 0; st < STEPS; ++st) {
        float2 pr = prepA[wave][st * 4 + g];
        float  wj = prepW[wave][st * 4 + g];
        v2f xv = xp[(size_t)st * 64];
        v2f invv = {pr.x, pr.x};
        v2f ntiv = {pr.y, pr.y};
        v2f u  = __builtin_elementwise_fma(xv, invv, ntiv);
        v2f q  = u * u;
        v2f arg = q * (v2f){NHALF_LOG2E, NHALF_LOG2E};
        v2f ev = {EXP2F(arg.x), EXP2F(arg.y)};
        v2f wv2 = {wj, wj};
        v2f pw = __builtin_elementwise_fma(-wv2, q, wv2);   // w*(1-q)
        acc = __builtin_elementwise_fma(pw, ev, acc);
    }

    // sum the 4 i-subgroups: lanes {p, p+16, p+32, p+48}
    float acc0 = acc.x, acc1 = acc.y;
    acc0 += __shfl_down(acc0, 32); acc0 += __shfl_down(acc0, 16);
    acc1 += __shfl_down(acc1, 32); acc1 += __shfl_down(acc1, 16);
    if (lane < 16) {
        float2* pp = (float2*)(part + (size_t)si * 16384 + o * 32) + p;
        *pp = make_float2(acc0, acc1);
    }
}

// ---------------------------------------------------------------------------
// Sum S partial slices (part layout [si][o][b]) + silu + LayerNorm(512).
// Block = batch row b, tid = o. Writes hT[o][b] (input layout for next wav).
// ---------------------------------------------------------------------------
template<int S>
__global__ __launch_bounds__(512)
void silu_ln(const float* __restrict__ part, const float* __restrict__ g,
             const float* __restrict__ bias, float* __restrict__ hT)
{
    const int b = blockIdx.x, tid = threadIdx.x;
    float v = 0.f;
#pragma unroll
    for (int si = 0; si < S; ++si) v += part[(size_t)si * 16384 + tid * 32 + b];
    float a = v * __builtin_amdgcn_rcpf(1.f + EXP2F(-v * LOG2E));  // silu

    float s1 = a, s2 = a * a;
#pragma unroll
    for (int off = 32; off; off >>= 1) {
        s1 += __shfl_down(s1, off);
        s2 += __shfl_down(s2, off);
    }
    __shared__ float r1[8], r2[8];
    const int lane = tid & 63, wid = tid >> 6;
    if (lane == 0) { r1[wid] = s1; r2[wid] = s2; }
    __syncthreads();
    float t1 = 0.f, t2 = 0.f;
#pragma unroll
    for (int k = 0; k < 8; ++k) { t1 += r1[k]; t2 += r2[k]; }
    float m   = t1 * (1.f / 512.f);
    float var = t2 * (1.f / 512.f) - m * m;
    float r   = __builtin_amdgcn_rsqf(var + LN_EPS);
    hT[tid * 32 + b] = (a - m) * r * g[tid] + bias[tid];
}

// ---------------------------------------------------------------------------
// Final: sum partials + silu + LN + classifier (out = hln @ cw.T + cb).
// ---------------------------------------------------------------------------
template<int S>
__global__ __launch_bounds__(512)
void silu_ln_cls(const float* __restrict__ part, const float* __restrict__ g,
                 const float* __restrict__ bias, const float* __restrict__ cw,
                 const float* __restrict__ cb, float* __restrict__ out)
{
    const int b = blockIdx.x, tid = threadIdx.x;
    float v = 0.f;
#pragma unroll
    for (int si = 0; si < S; ++si) v += part[(size_t)si * 16384 + tid * 32 + b];
    float a = v * __builtin_amdgcn_rcpf(1.f + EXP2F(-v * LOG2E));

    float s1 = a, s2 = a * a;
#pragma unroll
    for (int off = 32; off; off >>= 1) {
        s1 += __shfl_down(s1, off);
        s2 += __shfl_down(s2, off);
    }
    __shared__ float r1[8], r2[8];
    const int lane = tid & 63, wid = tid >> 6;
    if (lane == 0) { r1[wid] = s1; r2[wid] = s2; }
    __syncthreads();
    float t1 = 0.f, t2 = 0.f;
#pragma unroll
    for (int k = 0; k < 8; ++k) { t1 += r1[k]; t2 += r2[k]; }
    float m   = t1 * (1.f / 512.f);
    float var = t2 * (1.f / 512.f) - m * m;
    float r   = __builtin_amdgcn_rsqf(var + LN_EPS);
    float hl  = (a - m) * r * g[tid] + bias[tid];

    __shared__ float cr[5][8];
#pragma unroll
    for (int c = 0; c < 5; ++c) {
        float pv = hl * cw[c * 512 + tid];
#pragma unroll
        for (int off = 32; off; off >>= 1) pv += __shfl_down(pv, off);
        if (lane == 0) cr[c][wid] = pv;
    }
    __syncthreads();
    if (tid < 5) {
        float sum = 0.f;
#pragma unroll
        for (int k = 0; k < 8; ++k) sum += cr[tid][k];
        out[b * 5 + tid] = sum + cb[tid];
    }
}

extern "C" void kernel_launch(void* const* d_in, const int* in_sizes, int n_in,
                              void* d_out, int out_size, void* d_ws, size_t ws_size,
                              hipStream_t stream)
{
    const float* x  = (const float*)d_in[0];
    const float* w0 = (const float*)d_in[1];
    const float* t0 = (const float*)d_in[2];
    const float* s0 = (const float*)d_in[3];
    const float* g0 = (const float*)d_in[4];
    const float* b0 = (const float*)d_in[5];
    const float* w1 = (const float*)d_in[6];
    const float* t1 = (const float*)d_in[7];
    const float* s1 = (const float*)d_in[8];
    const float* b1 = (const float*)d_in[10];
    const float* g1 = (const float*)d_in[9];
    const float* w2 = (const float*)d_in[11];
    const float* t2 = (const float*)d_in[12];
    const float* s2 = (const float*)d_in[13];
    const float* g2 = (const float*)d_in[14];
    const float* b2 = (const float*)d_in[15];
    const float* cw = (const float*)d_in[16];
    const float* cb = (const float*)d_in[17];
    float* out = (float*)d_out;

    // ws layout (floats): xT 196608 | part 16*16384 | hT 16384  (~1.86 MB)
    float* xT   = (float*)d_ws;
    float* part = xT + 196608;
    float* hT   = part + 16 * 16384;

    transpose_x<6144><<<768, 256, 0, stream>>>(x, xT);
    wav_layer<6144, 16><<<dim3(256, 16), 128, 0, stream>>>(xT, w0, t0, s0, part);
    silu_ln<16><<<32, 512, 0, stream>>>(part, g0, b0, hT);
    wav_layer<512, 8><<<dim3(256, 8), 128, 0, stream>>>(hT, w1, t1, s1, part);
    silu_ln<8><<<32, 512, 0, stream>>>(part, g1, b1, hT);
    wav_layer<512, 8><<<dim3(256, 8), 128, 0, stream>>>(hT, w2, t2, s2, part);
    silu_ln_cls<8><<<32, 512, 0, stream>>>(part, g2, b2, cw, cb, out);
}